// Round 7
// baseline (17.766 us; speedup 1.0000x reference)
//
#include <hip/hip_runtime.h>

// PrimitiveCollisionCost: B=16 H=64 L=12 S=8 W=256, N = B*H = 1024
// Block = 512 thr (8 waves). Wave w: links (w&3)*3..+2, world half (w>>2)*128.
// Each lane holds 2 world spheres; per-link max combined across wave pairs in LDS.

#define NL 12
#define NS 8

__device__ __forceinline__ float fast_sqrtf(float x) {
    return __builtin_amdgcn_sqrtf(x);   // single v_sqrt_f32 (~1 ulp)
}

__global__ __launch_bounds__(512) void pcc_kernel(
    const float* __restrict__ pos,    // (N, L, 3)
    const float* __restrict__ rot,    // (N, L, 9)
    const float* __restrict__ lsph,   // (L, S, 4)
    const float* __restrict__ wsph,   // (W, 4)
    const float* __restrict__ weight, // scalar
    float* __restrict__ out)          // (N)
{
    const int n    = blockIdx.x;
    const int tid  = threadIdx.x;
    const int lane = tid & 63;
    const int wv   = tid >> 6;   // 0..7
    const int wl   = wv & 3;     // which link triple
    const int kh   = wv >> 2;    // which half of the 256 world spheres

    // 2 world spheres per lane, register-resident.
    const float4* wsph4 = reinterpret_cast<const float4*>(wsph);
    const float4 ws0 = wsph4[lane + 128 * kh];
    const float4 ws1 = wsph4[lane + 128 * kh + 64];
    const float wr0 = ws0.w, wr1 = ws1.w;

    const float4* lsph4 = reinterpret_cast<const float4*>(lsph);

    float m[3];
    m[0] = m[1] = m[2] = -1e30f;

#pragma unroll
    for (int li = 0; li < 3; ++li) {
        // Force wave-uniform index into SGPR -> rot/pos become s_loads.
        const int l = __builtin_amdgcn_readfirstlane(wl * 3 + li);
        const float* r = rot + ((size_t)n * NL + l) * 9;
        const float* p = pos + ((size_t)n * NL + l) * 3;
        const float r00 = r[0], r01 = r[1], r02 = r[2];
        const float r10 = r[3], r11 = r[4], r12 = r[5];
        const float r20 = r[6], r21 = r[7], r22 = r[8];
        const float px = p[0], py = p[1], pz = p[2];

#pragma unroll
        for (int s = 0; s < NS; ++s) {
            const float4 ls = lsph4[l * NS + s];
            const float cx = r00 * ls.x + r01 * ls.y + r02 * ls.z + px;
            const float cy = r10 * ls.x + r11 * ls.y + r12 * ls.z + py;
            const float cz = r20 * ls.x + r21 * ls.y + r22 * ls.z + pz;
            const float rr = ls.w;
            const float a0 = wr0 + rr, a1 = wr1 + rr;

            const float dx0 = cx - ws0.x, dy0 = cy - ws0.y, dz0 = cz - ws0.z;
            const float dx1 = cx - ws1.x, dy1 = cy - ws1.y, dz1 = cz - ws1.z;

            const float v0 = a0 - fast_sqrtf(dx0*dx0 + dy0*dy0 + dz0*dz0);
            const float v1 = a1 - fast_sqrtf(dx1*dx1 + dy1*dy1 + dz1*dz1);

            m[li] = fmaxf(m[li], fmaxf(v0, v1));   // -> v_max3_f32
        }
    }

    // Three interleaved 64-lane max butterflies.
#pragma unroll
    for (int off = 1; off < 64; off <<= 1) {
        m[0] = fmaxf(m[0], __shfl_xor(m[0], off));
        m[1] = fmaxf(m[1], __shfl_xor(m[1], off));
        m[2] = fmaxf(m[2], __shfl_xor(m[2], off));
    }

    __shared__ float partial[8][3];
    if (lane == 0) {
        partial[wv][0] = m[0];
        partial[wv][1] = m[1];
        partial[wv][2] = m[2];
    }
    __syncthreads();

    // Single-wave tail: lane l (<12) finalizes link l.
    if (wv == 0) {
        float d = 0.0f;
        if (lane < NL) {
            const int wl2 = lane / 3, li2 = lane % 3;
            const float mx = fmaxf(partial[wl2][li2], partial[wl2 + 4][li2]);
            d = fminf(fmaxf(mx + 0.1f, 0.0f), 0.2f) * 4.0f;  // clip/0.25
        }
#pragma unroll
        for (int off = 1; off < 16; off <<= 1)
            d += __shfl_xor(d, off, 16);
        if (lane == 0) out[n] = weight[0] * d;
    }
}

extern "C" void kernel_launch(void* const* d_in, const int* in_sizes, int n_in,
                              void* d_out, int out_size, void* d_ws, size_t ws_size,
                              hipStream_t stream) {
    const float* pos    = (const float*)d_in[0];
    const float* rot    = (const float*)d_in[1];
    const float* lsph   = (const float*)d_in[2];
    const float* wsph   = (const float*)d_in[3];
    const float* weight = (const float*)d_in[4];
    float* out = (float*)d_out;

    const int N = out_size; // 1024
    pcc_kernel<<<N, 512, 0, stream>>>(pos, rot, lsph, wsph, weight, out);
}

// Round 8
// 13.353 us; speedup vs baseline: 1.3305x; 1.3305x over previous
//
#include <hip/hip_runtime.h>

// PrimitiveCollisionCost: B=16 H=64 L=12 S=8 W=256, N = B*H = 1024
// One block (256 thr) per n.
// Phase 1: threads 0..95 compute world-frame centers (one per (l,s) pair) into LDS.
// Phase 2: wave w owns links 3w..3w+2; lane owns 4 world spheres (registers).
//          Distances read centers from LDS (wave-uniform addr -> broadcast).

#define NL 12
#define NS 8

__device__ __forceinline__ float fast_sqrtf(float x) {
    return __builtin_amdgcn_sqrtf(x);   // single v_sqrt_f32 (~1 ulp)
}

__global__ __launch_bounds__(256) void pcc_kernel(
    const float* __restrict__ pos,    // (N, L, 3)
    const float* __restrict__ rot,    // (N, L, 9)
    const float* __restrict__ lsph,   // (L, S, 4)
    const float* __restrict__ wsph,   // (W, 4)
    const float* __restrict__ weight, // scalar
    float* __restrict__ out)          // (N)
{
    const int n    = blockIdx.x;
    const int tid  = threadIdx.x;
    const int lane = tid & 63;
    const int wave = tid >> 6;   // 0..3, wave w owns links 3w..3w+2

    __shared__ float4 cen[NL * NS];   // (cx, cy, cz, rob_r) per (l,s)
    __shared__ float partial[4];

    // ---- Phase 1: 96 threads compute 96 centers (each once per block) ----
    if (tid < NL * NS) {
        const int l = tid >> 3;               // tid = l*8 + s
        const float* r = rot + ((size_t)n * NL + l) * 9;
        const float* p = pos + ((size_t)n * NL + l) * 3;
        const float4 ls = reinterpret_cast<const float4*>(lsph)[tid];
        const float cx = r[0]*ls.x + r[1]*ls.y + r[2]*ls.z + p[0];
        const float cy = r[3]*ls.x + r[4]*ls.y + r[5]*ls.z + p[1];
        const float cz = r[6]*ls.x + r[7]*ls.y + r[8]*ls.z + p[2];
        cen[tid] = make_float4(cx, cy, cz, ls.w);
    }

    // Each lane owns 4 world spheres, register-resident (overlaps phase 1).
    const float4* wsph4 = reinterpret_cast<const float4*>(wsph);
    const float4 ws0 = wsph4[lane];
    const float4 ws1 = wsph4[lane + 64];
    const float4 ws2 = wsph4[lane + 128];
    const float4 ws3 = wsph4[lane + 192];

    __syncthreads();

    // ---- Phase 2: pure LDS + VALU distance/max ----
    float m[3];
    m[0] = m[1] = m[2] = -1e30f;
    const float4* base = &cen[wave * 24];

#pragma unroll
    for (int li = 0; li < 3; ++li) {
#pragma unroll
        for (int s = 0; s < NS; ++s) {
            const float4 c = base[li * NS + s];   // broadcast read
            const float rr = c.w;

            const float dx0 = c.x - ws0.x, dy0 = c.y - ws0.y, dz0 = c.z - ws0.z;
            const float dx1 = c.x - ws1.x, dy1 = c.y - ws1.y, dz1 = c.z - ws1.z;
            const float dx2 = c.x - ws2.x, dy2 = c.y - ws2.y, dz2 = c.z - ws2.z;
            const float dx3 = c.x - ws3.x, dy3 = c.y - ws3.y, dz3 = c.z - ws3.z;

            const float v0 = ws0.w + rr - fast_sqrtf(dx0*dx0 + dy0*dy0 + dz0*dz0);
            const float v1 = ws1.w + rr - fast_sqrtf(dx1*dx1 + dy1*dy1 + dz1*dz1);
            const float v2 = ws2.w + rr - fast_sqrtf(dx2*dx2 + dy2*dy2 + dz2*dz2);
            const float v3 = ws3.w + rr - fast_sqrtf(dx3*dx3 + dy3*dy3 + dz3*dz3);

            // two v_max3_f32
            m[li] = fmaxf(fmaxf(m[li], v0), v1);
            m[li] = fmaxf(fmaxf(m[li], v2), v3);
        }
    }

    // Three interleaved 64-lane max butterflies.
#pragma unroll
    for (int off = 1; off < 64; off <<= 1) {
        m[0] = fmaxf(m[0], __shfl_xor(m[0], off));
        m[1] = fmaxf(m[1], __shfl_xor(m[1], off));
        m[2] = fmaxf(m[2], __shfl_xor(m[2], off));
    }

    // d = clip(m + 0.1, 0, 0.2) / 0.25  (== clamp * 4)
    const float acc = fminf(fmaxf(m[0] + 0.1f, 0.0f), 0.2f) * 4.0f
                    + fminf(fmaxf(m[1] + 0.1f, 0.0f), 0.2f) * 4.0f
                    + fminf(fmaxf(m[2] + 0.1f, 0.0f), 0.2f) * 4.0f;

    if (lane == 0) partial[wave] = acc;
    __syncthreads();
    if (tid == 0)
        out[n] = weight[0] * (partial[0] + partial[1] + partial[2] + partial[3]);
}

extern "C" void kernel_launch(void* const* d_in, const int* in_sizes, int n_in,
                              void* d_out, int out_size, void* d_ws, size_t ws_size,
                              hipStream_t stream) {
    const float* pos    = (const float*)d_in[0];
    const float* rot    = (const float*)d_in[1];
    const float* lsph   = (const float*)d_in[2];
    const float* wsph   = (const float*)d_in[3];
    const float* weight = (const float*)d_in[4];
    float* out = (float*)d_out;

    const int N = out_size; // 1024
    pcc_kernel<<<N, 256, 0, stream>>>(pos, rot, lsph, wsph, weight, out);
}